// Round 3
// baseline (138.234 us; speedup 1.0000x reference)
//
#include <hip/hip_runtime.h>
#include <math.h>

#define N_SAMPLES 8192
#define DIM 128
#define NCLS 1024
#define MARGIN_V 0.3f
#define DIST_GX (N_SAMPLES / 128)   // 64
#define DIST_GY (NCLS / 128)        // 8
#define DIST_BLOCKS (DIST_GX * DIST_GY)

using bf16x8 = __attribute__((ext_vector_type(8))) short;
using f32x16 = __attribute__((ext_vector_type(16))) float;
using short8 = __attribute__((ext_vector_type(8))) short;

// ---- monotonic float<->uint encoding for atomic max/min on floats ----
__device__ __forceinline__ unsigned enc_f(float f) {
  unsigned b = __float_as_uint(f);
  return (b & 0x80000000u) ? ~b : (b | 0x80000000u);
}
__device__ __forceinline__ float dec_f(unsigned u) {
  unsigned b = (u & 0x80000000u) ? (u & 0x7FFFFFFFu) : ~u;
  return __uint_as_float(b);
}

__device__ __forceinline__ short bf16_rne(float x) {
  unsigned u = __float_as_uint(x);
  unsigned r = u + 0x7FFFu + ((u >> 16) & 1u);
  return (short)(r >> 16);
}
__device__ __forceinline__ float bf16_tof(short h) {
  return __uint_as_float(((unsigned)(unsigned short)h) << 16);
}

// Packed fragment layout (row-major source [row][k=0..127]):
//   tile = row>>5, kstep = oct>>1 (oct = k/8), lane = ((oct&1)<<5)|(row&31)
//   short8 index = ((tile*8 + kstep)*2 + plane)*64 + lane
// plane 0 = hi bf16, plane 1 = lo bf16. Matches mfma_32x32x16 A/B operand
// layout operand[row=lane&31][k=(lane>>5)*8+j]  (verified: R1 absmax 0.0).
__device__ __forceinline__ size_t frag_idx(int row, int oct) {
  int tile = row >> 5, ks = oct >> 1, lane = ((oct & 1) << 5) | (row & 31);
  return (size_t)((tile * 8 + ks) * 2) * 64 + lane;
}

// K1: single block, 1024 threads. Histogram -> scan -> member scatter,
// plus all per-launch init (dp/dn sentinels, done counter).
__global__ __launch_bounds__(1024) void sort_init_kernel(
    const int* __restrict__ targets, int* __restrict__ counts,
    int* __restrict__ offsets, int* __restrict__ members,
    unsigned* __restrict__ dpbits, unsigned* __restrict__ dnbits,
    int* __restrict__ done) {
  __shared__ int buf[NCLS];
  __shared__ int cur[NCLS];
  int t = threadIdx.x;
  buf[t] = 0;
  dpbits[t] = enc_f(-INFINITY);
  dnbits[t] = enc_f(INFINITY);
  if (t == 0) *done = 0;
  __syncthreads();
  int tg[8];
  #pragma unroll
  for (int i = 0; i < 8; i++) {
    tg[i] = targets[t + NCLS * i];
    atomicAdd(&buf[tg[i]], 1);
  }
  __syncthreads();
  int cnt = buf[t];
  counts[t] = cnt;
  // Hillis-Steele inclusive scan over buf
  for (int off = 1; off < NCLS; off <<= 1) {
    int add = (t >= off) ? buf[t - off] : 0;
    __syncthreads();
    buf[t] += add;
    __syncthreads();
  }
  int excl = buf[t] - cnt;
  offsets[t] = excl;
  cur[t] = excl;
  __syncthreads();
  #pragma unroll
  for (int i = 0; i < 8; i++) {
    int pos = atomicAdd(&cur[tg[i]], 1);
    members[pos] = t + NCLS * i;
  }
}

// K2: fused pack. Blocks [0,512): B-side (x2 + hi/lo pack of inputs).
// Blocks [512,1024): A-side (center gather-sum, c2, hi/lo pack), 2 classes/block.
__global__ __launch_bounds__(256) void pack_kernel(
    const float* __restrict__ inputs, const int* __restrict__ members,
    const int* __restrict__ offsets, const int* __restrict__ counts,
    float* __restrict__ x2, float* __restrict__ c2,
    short8* __restrict__ Apk, short8* __restrict__ Bpk) {
  int b = blockIdx.x;
  int tid = threadIdx.x;
  if (b < N_SAMPLES / 16) {
    int row = b * 16 + (tid >> 4);
    int oct = tid & 15;
    const float4* p = (const float4*)(inputs + (size_t)row * DIM + oct * 8);
    float4 v0 = p[0], v1 = p[1];
    float v[8] = {v0.x, v0.y, v0.z, v0.w, v1.x, v1.y, v1.z, v1.w};
    float s = 0.f;
    #pragma unroll
    for (int i = 0; i < 8; i++) s += v[i] * v[i];
    #pragma unroll
    for (int m = 1; m < 16; m <<= 1) s += __shfl_xor(s, m);
    if (oct == 0) x2[row] = s;
    short8 hi, lo;
    #pragma unroll
    for (int i = 0; i < 8; i++) {
      short h = bf16_rne(v[i]);
      hi[i] = h;
      lo[i] = bf16_rne(v[i] - bf16_tof(h));
    }
    size_t fi = frag_idx(row, oct);
    Bpk[fi] = hi;
    Bpk[fi + 64] = lo;
  } else {
    __shared__ float sctr[2][128];
    __shared__ float wsum[4];
    int half = tid >> 7;                       // which class of the pair
    int c = (b - N_SAMPLES / 16) * 2 + half;
    int d = tid & 127;
    int off = offsets[c];
    int cnt = counts[c];
    float acc = 0.f;
    for (int m = 0; m < cnt; m++) {
      acc += inputs[(size_t)members[off + m] * DIM + d];
    }
    float ctr = (cnt > 0) ? acc / (float)cnt : 0.f;
    sctr[half][d] = ctr;
    float vv = ctr * ctr;
    #pragma unroll
    for (int sh = 32; sh > 0; sh >>= 1) vv += __shfl_down(vv, sh);
    if ((tid & 63) == 0) wsum[tid >> 6] = vv;
    __syncthreads();
    if (d == 0) c2[c] = wsum[half * 2] + wsum[half * 2 + 1];
    if (d < 16) {
      int oct = d;
      float pv[8];
      #pragma unroll
      for (int i = 0; i < 8; i++) pv[i] = sctr[half][oct * 8 + i];
      short8 hi, lo;
      #pragma unroll
      for (int i = 0; i < 8; i++) {
        short h = bf16_rne(pv[i]);
        hi[i] = h;
        lo[i] = bf16_rne(pv[i] - bf16_tof(h));
      }
      size_t fi = frag_idx(c, oct);
      Apk[fi] = hi;
      Apk[fi + 64] = lo;
    }
  }
}

// K3: MFMA dist (128x128 tile, 4 waves of 64x64 = 2x2 32x32x16) with
// split-bf16 (hi*hi + hi*lo + lo*hi) and last-block-fused finalize.
__global__ __launch_bounds__(256) void dist_kernel(
    const short8* __restrict__ Apk, const short8* __restrict__ Bpk,
    const float* __restrict__ x2, const float* __restrict__ c2,
    const int* __restrict__ targets, const int* __restrict__ counts,
    unsigned* dpbits, unsigned* dnbits, int* done, float* __restrict__ out) {
  __shared__ float sc2[128];
  __shared__ float sx2[128];
  __shared__ int stgt[128];
  __shared__ int lastFlag;
  __shared__ float sl[4], sp[4];

  int tid = threadIdx.x;
  int jbase = blockIdx.x * 128;
  int cbase = blockIdx.y * 128;
  int wave = tid >> 6, lane = tid & 63;
  int wm = wave >> 1, wn = wave & 1;

  if (tid < 128) {
    sc2[tid] = c2[cbase + tid];
    sx2[tid] = x2[jbase + tid];
    stgt[tid] = targets[jbase + tid];
  }

  f32x16 acc[2][2];
  #pragma unroll
  for (int i = 0; i < 2; i++)
    #pragma unroll
    for (int j = 0; j < 2; j++)
      acc[i][j] = (f32x16)(0.f);

  int mtg0 = (cbase >> 5) + wm * 2;
  int ntg0 = (jbase >> 5) + wn * 2;

  #pragma unroll 2
  for (int ks = 0; ks < 8; ks++) {
    bf16x8 a[2][2], b[2][2];  // [tile][plane]
    #pragma unroll
    for (int mt = 0; mt < 2; mt++) {
      size_t base = (size_t)(((mtg0 + mt) * 8 + ks) * 2) * 64 + lane;
      a[mt][0] = Apk[base];
      a[mt][1] = Apk[base + 64];
    }
    #pragma unroll
    for (int nt = 0; nt < 2; nt++) {
      size_t base = (size_t)(((ntg0 + nt) * 8 + ks) * 2) * 64 + lane;
      b[nt][0] = Bpk[base];
      b[nt][1] = Bpk[base + 64];
    }
    #pragma unroll
    for (int mt = 0; mt < 2; mt++)
      #pragma unroll
      for (int nt = 0; nt < 2; nt++) {
        acc[mt][nt] = __builtin_amdgcn_mfma_f32_32x32x16_bf16(a[mt][0], b[nt][0], acc[mt][nt], 0, 0, 0);
        acc[mt][nt] = __builtin_amdgcn_mfma_f32_32x32x16_bf16(a[mt][0], b[nt][1], acc[mt][nt], 0, 0, 0);
        acc[mt][nt] = __builtin_amdgcn_mfma_f32_32x32x16_bf16(a[mt][1], b[nt][0], acc[mt][nt], 0, 0, 0);
      }
  }

  __syncthreads();  // staging visible

  int hf = lane >> 5;
  int col = lane & 31;
  #pragma unroll
  for (int mt = 0; mt < 2; mt++) {
    #pragma unroll
    for (int r = 0; r < 16; r++) {
      int rowl = (r & 3) + 8 * (r >> 2) + 4 * hf;
      int c_loc = wm * 64 + mt * 32 + rowl;
      int cg = cbase + c_loc;
      float c2v = sc2[c_loc];
      float pmax = -INFINITY, nmin = INFINITY;
      #pragma unroll
      for (int nt = 0; nt < 2; nt++) {
        int j_loc = wn * 64 + nt * 32 + col;
        float d2 = c2v + sx2[j_loc] - 2.f * acc[mt][nt][r];
        if (stgt[j_loc] == cg) pmax = fmaxf(pmax, d2);
        else                   nmin = fminf(nmin, d2);
      }
      #pragma unroll
      for (int m = 1; m < 32; m <<= 1) {
        pmax = fmaxf(pmax, __shfl_xor(pmax, m));
        nmin = fminf(nmin, __shfl_xor(nmin, m));
      }
      if (col == 0) {
        atomicMax(&dpbits[cg], enc_f(pmax));
        atomicMin(&dnbits[cg], enc_f(nmin));
      }
    }
  }

  // ---- last-block finalize ----
  __threadfence();   // order this thread's dp/dn atomics before done-count
  __syncthreads();   // all threads of block have issued + fenced
  if (tid == 0) {
    int prev = atomicAdd(done, 1);
    lastFlag = (prev == DIST_BLOCKS - 1) ? 1 : 0;
  }
  __syncthreads();
  if (!lastFlag) return;
  __threadfence();

  float ls = 0.f, ps = 0.f;
  for (int cc = tid; cc < NCLS; cc += 256) {
    int cnt = counts[cc];
    // no-op atomics = coherent cross-XCD read (enc values are > 0)
    float dp = dec_f(atomicMax(&dpbits[cc], 0u));
    float dn = dec_f(atomicMin(&dnbits[cc], 0xFFFFFFFFu));
    if (cnt > 0) {
      ls += (float)cnt * fmaxf(dp - dn + MARGIN_V, 0.f);
      ps += (float)cnt * ((dn > dp) ? 1.f : 0.f);
    }
  }
  #pragma unroll
  for (int sh = 32; sh > 0; sh >>= 1) {
    ls += __shfl_down(ls, sh);
    ps += __shfl_down(ps, sh);
  }
  if (lane == 0) { sl[wave] = ls; sp[wave] = ps; }
  __syncthreads();
  if (tid == 0) {
    out[0] = (sl[0] + sl[1] + sl[2] + sl[3]) / (float)N_SAMPLES;
    out[1] = (sp[0] + sp[1] + sp[2] + sp[3]) / (float)N_SAMPLES;
  }
}

extern "C" void kernel_launch(void* const* d_in, const int* in_sizes, int n_in,
                              void* d_out, int out_size, void* d_ws, size_t ws_size,
                              hipStream_t stream) {
  const float* inputs = (const float*)d_in[0];
  const int* targets = (const int*)d_in[1];
  float* out = (float*)d_out;

  char* w = (char*)d_ws;
  float* x2 = (float*)w;            w += (size_t)N_SAMPLES * 4;
  float* c2 = (float*)w;            w += (size_t)NCLS * 4;
  int* counts = (int*)w;            w += (size_t)NCLS * 4;
  int* offsets = (int*)w;           w += (size_t)NCLS * 4;
  int* members = (int*)w;           w += (size_t)N_SAMPLES * 4;
  unsigned* dpbits = (unsigned*)w;  w += (size_t)NCLS * 4;
  unsigned* dnbits = (unsigned*)w;  w += (size_t)NCLS * 4;
  int* done = (int*)w;              w += 256;  // keep following buffers aligned
  short8* Apk = (short8*)w;         w += (size_t)NCLS * DIM * 2 * 2;      // 512 KB
  short8* Bpk = (short8*)w;         w += (size_t)N_SAMPLES * DIM * 2 * 2; // 4 MB

  sort_init_kernel<<<1, 1024, 0, stream>>>(targets, counts, offsets, members,
                                           dpbits, dnbits, done);
  pack_kernel<<<N_SAMPLES / 16 + NCLS / 2, 256, 0, stream>>>(
      inputs, members, offsets, counts, x2, c2, Apk, Bpk);
  dist_kernel<<<dim3(DIST_GX, DIST_GY), 256, 0, stream>>>(
      Apk, Bpk, x2, c2, targets, counts, dpbits, dnbits, done, out);
}

// Round 4
// 106.755 us; speedup vs baseline: 1.2949x; 1.2949x over previous
//
#include <hip/hip_runtime.h>
#include <math.h>

#define N_SAMPLES 8192
#define DIM 128
#define NCLS 1024
#define MARGIN_V 0.3f
#define DIST_GX (N_SAMPLES / 128)   // 64
#define DIST_GY (NCLS / 128)        // 8
#define NPART (DIST_GX * 2)         // 128 partials per class (2 j-halves per block)

using bf16x8 = __attribute__((ext_vector_type(8))) short;
using f32x16 = __attribute__((ext_vector_type(16))) float;
using short8 = __attribute__((ext_vector_type(8))) short;

__device__ __forceinline__ short bf16_rne(float x) {
  unsigned u = __float_as_uint(x);
  unsigned r = u + 0x7FFFu + ((u >> 16) & 1u);
  return (short)(r >> 16);
}
__device__ __forceinline__ float bf16_tof(short h) {
  return __uint_as_float(((unsigned)(unsigned short)h) << 16);
}

// Packed fragment layout (row-major source [row][k=0..127]):
//   tile = row>>5, kstep = oct>>1 (oct = k/8), lane = ((oct&1)<<5)|(row&31)
//   short8 index = ((tile*8 + kstep)*2 + plane)*64 + lane
// plane 0 = hi bf16, plane 1 = lo bf16. Matches mfma_32x32x16 A/B operand
// layout operand[row=lane&31][k=(lane>>5)*8+j]  (verified: R1/R2 absmax 0.0).
__device__ __forceinline__ size_t frag_idx(int row, int oct) {
  int tile = row >> 5, ks = oct >> 1, lane = ((oct & 1) << 5) | (row & 31);
  return (size_t)((tile * 8 + ks) * 2) * 64 + lane;
}

// K1: single block, 1024 threads. Histogram -> scan -> member scatter.
__global__ __launch_bounds__(1024) void sort_init_kernel(
    const int* __restrict__ targets, int* __restrict__ counts,
    int* __restrict__ offsets, int* __restrict__ members) {
  __shared__ int buf[NCLS];
  __shared__ int cur[NCLS];
  int t = threadIdx.x;
  buf[t] = 0;
  __syncthreads();
  int tg[8];
  #pragma unroll
  for (int i = 0; i < 8; i++) {
    tg[i] = targets[t + NCLS * i];
    atomicAdd(&buf[tg[i]], 1);
  }
  __syncthreads();
  int cnt = buf[t];
  counts[t] = cnt;
  for (int off = 1; off < NCLS; off <<= 1) {
    int add = (t >= off) ? buf[t - off] : 0;
    __syncthreads();
    buf[t] += add;
    __syncthreads();
  }
  int excl = buf[t] - cnt;
  offsets[t] = excl;
  cur[t] = excl;
  __syncthreads();
  #pragma unroll
  for (int i = 0; i < 8; i++) {
    int pos = atomicAdd(&cur[tg[i]], 1);
    members[pos] = t + NCLS * i;
  }
}

// K2: fused pack. Blocks [0,512): B-side (x2 + hi/lo pack of inputs).
// Blocks [512,1024): A-side (center gather-sum, c2, hi/lo pack), 2 classes/block.
__global__ __launch_bounds__(256) void pack_kernel(
    const float* __restrict__ inputs, const int* __restrict__ members,
    const int* __restrict__ offsets, const int* __restrict__ counts,
    float* __restrict__ x2, float* __restrict__ c2,
    short8* __restrict__ Apk, short8* __restrict__ Bpk) {
  int b = blockIdx.x;
  int tid = threadIdx.x;
  if (b < N_SAMPLES / 16) {
    int row = b * 16 + (tid >> 4);
    int oct = tid & 15;
    const float4* p = (const float4*)(inputs + (size_t)row * DIM + oct * 8);
    float4 v0 = p[0], v1 = p[1];
    float v[8] = {v0.x, v0.y, v0.z, v0.w, v1.x, v1.y, v1.z, v1.w};
    float s = 0.f;
    #pragma unroll
    for (int i = 0; i < 8; i++) s += v[i] * v[i];
    #pragma unroll
    for (int m = 1; m < 16; m <<= 1) s += __shfl_xor(s, m);
    if (oct == 0) x2[row] = s;
    short8 hi, lo;
    #pragma unroll
    for (int i = 0; i < 8; i++) {
      short h = bf16_rne(v[i]);
      hi[i] = h;
      lo[i] = bf16_rne(v[i] - bf16_tof(h));
    }
    size_t fi = frag_idx(row, oct);
    Bpk[fi] = hi;
    Bpk[fi + 64] = lo;
  } else {
    __shared__ float sctr[2][128];
    __shared__ float wsum[4];
    int half = tid >> 7;
    int c = (b - N_SAMPLES / 16) * 2 + half;
    int d = tid & 127;
    int off = offsets[c];
    int cnt = counts[c];
    float acc = 0.f;
    for (int m = 0; m < cnt; m++) {
      acc += inputs[(size_t)members[off + m] * DIM + d];
    }
    float ctr = (cnt > 0) ? acc / (float)cnt : 0.f;
    sctr[half][d] = ctr;
    float vv = ctr * ctr;
    #pragma unroll
    for (int sh = 32; sh > 0; sh >>= 1) vv += __shfl_down(vv, sh);
    if ((tid & 63) == 0) wsum[tid >> 6] = vv;
    __syncthreads();
    if (d == 0) c2[c] = wsum[half * 2] + wsum[half * 2 + 1];
    if (d < 16) {
      int oct = d;
      float pv[8];
      #pragma unroll
      for (int i = 0; i < 8; i++) pv[i] = sctr[half][oct * 8 + i];
      short8 hi, lo;
      #pragma unroll
      for (int i = 0; i < 8; i++) {
        short h = bf16_rne(pv[i]);
        hi[i] = h;
        lo[i] = bf16_rne(pv[i] - bf16_tof(h));
      }
      size_t fi = frag_idx(c, oct);
      Apk[fi] = hi;
      Apk[fi + 64] = lo;
    }
  }
}

// K3: MFMA dist (128x128 tile, 4 waves of 64x64 = 2x2 32x32x16), split-bf16.
// Epilogue: per-block per-class partial max/min via PLAIN stores (no atomics,
// no fences). Slot: part[(bx*2 + wn)*NCLS + cls]; every slot is written.
__global__ __launch_bounds__(256) void dist_kernel(
    const short8* __restrict__ Apk, const short8* __restrict__ Bpk,
    const float* __restrict__ x2, const float* __restrict__ c2,
    const int* __restrict__ targets,
    float* __restrict__ dp_part, float* __restrict__ dn_part) {
  __shared__ float sc2[128];
  __shared__ float sx2[128];
  __shared__ int stgt[128];

  int tid = threadIdx.x;
  int jbase = blockIdx.x * 128;
  int cbase = blockIdx.y * 128;
  int wave = tid >> 6, lane = tid & 63;
  int wm = wave >> 1, wn = wave & 1;

  if (tid < 128) {
    sc2[tid] = c2[cbase + tid];
    sx2[tid] = x2[jbase + tid];
    stgt[tid] = targets[jbase + tid];
  }

  f32x16 acc[2][2];
  #pragma unroll
  for (int i = 0; i < 2; i++)
    #pragma unroll
    for (int j = 0; j < 2; j++)
      acc[i][j] = (f32x16)(0.f);

  int mtg0 = (cbase >> 5) + wm * 2;
  int ntg0 = (jbase >> 5) + wn * 2;

  #pragma unroll 2
  for (int ks = 0; ks < 8; ks++) {
    bf16x8 a[2][2], b[2][2];  // [tile][plane]
    #pragma unroll
    for (int mt = 0; mt < 2; mt++) {
      size_t base = (size_t)(((mtg0 + mt) * 8 + ks) * 2) * 64 + lane;
      a[mt][0] = Apk[base];
      a[mt][1] = Apk[base + 64];
    }
    #pragma unroll
    for (int nt = 0; nt < 2; nt++) {
      size_t base = (size_t)(((ntg0 + nt) * 8 + ks) * 2) * 64 + lane;
      b[nt][0] = Bpk[base];
      b[nt][1] = Bpk[base + 64];
    }
    #pragma unroll
    for (int mt = 0; mt < 2; mt++)
      #pragma unroll
      for (int nt = 0; nt < 2; nt++) {
        acc[mt][nt] = __builtin_amdgcn_mfma_f32_32x32x16_bf16(a[mt][0], b[nt][0], acc[mt][nt], 0, 0, 0);
        acc[mt][nt] = __builtin_amdgcn_mfma_f32_32x32x16_bf16(a[mt][0], b[nt][1], acc[mt][nt], 0, 0, 0);
        acc[mt][nt] = __builtin_amdgcn_mfma_f32_32x32x16_bf16(a[mt][1], b[nt][0], acc[mt][nt], 0, 0, 0);
      }
  }

  __syncthreads();  // staging visible

  int hf = lane >> 5;
  int col = lane & 31;
  size_t pbase = (size_t)(blockIdx.x * 2 + wn) * NCLS + cbase;
  #pragma unroll
  for (int mt = 0; mt < 2; mt++) {
    #pragma unroll
    for (int r = 0; r < 16; r++) {
      int rowl = (r & 3) + 8 * (r >> 2) + 4 * hf;
      int c_loc = wm * 64 + mt * 32 + rowl;
      int cg = cbase + c_loc;
      float c2v = sc2[c_loc];
      float pmax = -INFINITY, nmin = INFINITY;
      #pragma unroll
      for (int nt = 0; nt < 2; nt++) {
        int j_loc = wn * 64 + nt * 32 + col;
        float d2 = c2v + sx2[j_loc] - 2.f * acc[mt][nt][r];
        if (stgt[j_loc] == cg) pmax = fmaxf(pmax, d2);
        else                   nmin = fminf(nmin, d2);
      }
      #pragma unroll
      for (int m = 1; m < 32; m <<= 1) {
        pmax = fmaxf(pmax, __shfl_xor(pmax, m));
        nmin = fminf(nmin, __shfl_xor(nmin, m));
      }
      if (col == 0) {
        dp_part[pbase + c_loc] = pmax;
        dn_part[pbase + c_loc] = nmin;
      }
    }
  }
}

// K4: one block, 1024 threads (thread = class). Reduce 128 partials per class
// (coalesced: consecutive threads read consecutive addresses), then weighted
// block reduction -> loss, prec.
__global__ __launch_bounds__(1024) void finalize_kernel(
    const float* __restrict__ dp_part, const float* __restrict__ dn_part,
    const int* __restrict__ counts, float* __restrict__ out) {
  int c = threadIdx.x;
  float dp = -INFINITY, dn = INFINITY;
  for (int p = 0; p < NPART; p++) {
    dp = fmaxf(dp, dp_part[(size_t)p * NCLS + c]);
    dn = fminf(dn, dn_part[(size_t)p * NCLS + c]);
  }
  int cnt = counts[c];
  float ls = 0.f, ps = 0.f;
  if (cnt > 0) {
    ls = (float)cnt * fmaxf(dp - dn + MARGIN_V, 0.f);
    ps = (float)cnt * ((dn > dp) ? 1.f : 0.f);
  }
  #pragma unroll
  for (int sh = 32; sh > 0; sh >>= 1) {
    ls += __shfl_down(ls, sh);
    ps += __shfl_down(ps, sh);
  }
  __shared__ float sl[16], sp[16];
  int wave = c >> 6, lane = c & 63;
  if (lane == 0) { sl[wave] = ls; sp[wave] = ps; }
  __syncthreads();
  if (c == 0) {
    float L = 0.f, P = 0.f;
    #pragma unroll
    for (int i = 0; i < 16; i++) { L += sl[i]; P += sp[i]; }
    out[0] = L / (float)N_SAMPLES;
    out[1] = P / (float)N_SAMPLES;
  }
}

extern "C" void kernel_launch(void* const* d_in, const int* in_sizes, int n_in,
                              void* d_out, int out_size, void* d_ws, size_t ws_size,
                              hipStream_t stream) {
  const float* inputs = (const float*)d_in[0];
  const int* targets = (const int*)d_in[1];
  float* out = (float*)d_out;

  char* w = (char*)d_ws;
  float* x2 = (float*)w;            w += (size_t)N_SAMPLES * 4;
  float* c2 = (float*)w;            w += (size_t)NCLS * 4;
  int* counts = (int*)w;            w += (size_t)NCLS * 4;
  int* offsets = (int*)w;           w += (size_t)NCLS * 4;
  int* members = (int*)w;           w += (size_t)N_SAMPLES * 4;
  float* dp_part = (float*)w;       w += (size_t)NPART * NCLS * 4;      // 512 KB
  float* dn_part = (float*)w;       w += (size_t)NPART * NCLS * 4;      // 512 KB
  short8* Apk = (short8*)w;         w += (size_t)NCLS * DIM * 2 * 2;    // 512 KB
  short8* Bpk = (short8*)w;         w += (size_t)N_SAMPLES * DIM * 2 * 2;  // 4 MB

  sort_init_kernel<<<1, 1024, 0, stream>>>(targets, counts, offsets, members);
  pack_kernel<<<N_SAMPLES / 16 + NCLS / 2, 256, 0, stream>>>(
      inputs, members, offsets, counts, x2, c2, Apk, Bpk);
  dist_kernel<<<dim3(DIST_GX, DIST_GY), 256, 0, stream>>>(
      Apk, Bpk, x2, c2, targets, dp_part, dn_part);
  finalize_kernel<<<1, 1024, 0, stream>>>(dp_part, dn_part, counts, out);
}

// Round 5
// 93.780 us; speedup vs baseline: 1.4740x; 1.1384x over previous
//
#include <hip/hip_runtime.h>
#include <math.h>

#define N_SAMPLES 8192
#define DIM 128
#define NCLS 1024
#define MARGIN_V 0.3f
#define DIST_GX (N_SAMPLES / 128)   // 64
#define DIST_GY (NCLS / 128)        // 8
#define NPART DIST_GX               // 64 partials per class (j-halves merged in LDS)
#define MAXMEM 64                   // LDS member-list capacity per class

using bf16x8 = __attribute__((ext_vector_type(8))) short;
using f32x16 = __attribute__((ext_vector_type(16))) float;
using short8 = __attribute__((ext_vector_type(8))) short;

__device__ __forceinline__ short bf16_rne(float x) {
  unsigned u = __float_as_uint(x);
  unsigned r = u + 0x7FFFu + ((u >> 16) & 1u);
  return (short)(r >> 16);
}
__device__ __forceinline__ float bf16_tof(short h) {
  return __uint_as_float(((unsigned)(unsigned short)h) << 16);
}

// Packed fragment layout (row-major source [row][k=0..127]):
//   tile = row>>5, kstep = oct>>1 (oct = k/8), lane = ((oct&1)<<5)|(row&31)
//   short8 index = ((tile*8 + kstep)*2 + plane)*64 + lane
// plane 0 = hi bf16, plane 1 = lo bf16. Matches mfma_32x32x16 A/B operand
// layout operand[row=lane&31][k=(lane>>5)*8+j]  (verified: R1-R4 absmax 0.0).
__device__ __forceinline__ size_t frag_idx(int row, int oct) {
  int tile = row >> 5, ks = oct >> 1, lane = ((oct & 1) << 5) | (row & 31);
  return (size_t)((tile * 8 + ks) * 2) * 64 + lane;
}

// K1: fused pack, no pre-sort needed.
// Blocks [0,512): B-side — x2 + hi/lo pack of 16 input rows.
// Blocks [512,1024): A-side — 2 classes/block: scan all targets into LDS
// member lists, gather-sum center, c2, counts, hi/lo pack.
__global__ __launch_bounds__(256) void pack_kernel(
    const float* __restrict__ inputs, const int* __restrict__ targets,
    float* __restrict__ x2, float* __restrict__ c2, int* __restrict__ counts,
    short8* __restrict__ Apk, short8* __restrict__ Bpk) {
  int b = blockIdx.x;
  int tid = threadIdx.x;
  if (b < N_SAMPLES / 16) {
    int row = b * 16 + (tid >> 4);
    int oct = tid & 15;
    const float4* p = (const float4*)(inputs + (size_t)row * DIM + oct * 8);
    float4 v0 = p[0], v1 = p[1];
    float v[8] = {v0.x, v0.y, v0.z, v0.w, v1.x, v1.y, v1.z, v1.w};
    float s = 0.f;
    #pragma unroll
    for (int i = 0; i < 8; i++) s += v[i] * v[i];
    #pragma unroll
    for (int m = 1; m < 16; m <<= 1) s += __shfl_xor(s, m);
    if (oct == 0) x2[row] = s;
    short8 hi, lo;
    #pragma unroll
    for (int i = 0; i < 8; i++) {
      short h = bf16_rne(v[i]);
      hi[i] = h;
      lo[i] = bf16_rne(v[i] - bf16_tof(h));
    }
    size_t fi = frag_idx(row, oct);
    Bpk[fi] = hi;
    Bpk[fi + 64] = lo;
  } else {
    __shared__ int mem[2][MAXMEM];
    __shared__ int mcnt[2];
    __shared__ float sctr[2][128];
    __shared__ float wsum[4];
    int c0 = (b - N_SAMPLES / 16) * 2;
    if (tid < 2) mcnt[tid] = 0;
    __syncthreads();
    // scan all 8192 targets, collect members of classes c0, c0+1
    #pragma unroll
    for (int i = 0; i < N_SAMPLES / 256; i++) {
      int idx = tid + 256 * i;
      int tg = targets[idx];
      if (tg == c0) {
        int p = atomicAdd(&mcnt[0], 1);
        if (p < MAXMEM) mem[0][p] = idx;
      } else if (tg == c0 + 1) {
        int p = atomicAdd(&mcnt[1], 1);
        if (p < MAXMEM) mem[1][p] = idx;
      }
    }
    __syncthreads();
    int half = tid >> 7;
    int c = c0 + half;
    int d = tid & 127;
    int cnt = mcnt[half];
    int cl = (cnt < MAXMEM) ? cnt : MAXMEM;
    float acc = 0.f;
    for (int m = 0; m < cl; m++) {
      acc += inputs[(size_t)mem[half][m] * DIM + d];
    }
    float ctr = (cnt > 0) ? acc / (float)cnt : 0.f;
    sctr[half][d] = ctr;
    float vv = ctr * ctr;
    #pragma unroll
    for (int sh = 32; sh > 0; sh >>= 1) vv += __shfl_down(vv, sh);
    if ((tid & 63) == 0) wsum[tid >> 6] = vv;
    __syncthreads();
    if (d == 0) {
      c2[c] = wsum[half * 2] + wsum[half * 2 + 1];
      counts[c] = cnt;
    }
    if (d < 16) {
      int oct = d;
      float pv[8];
      #pragma unroll
      for (int i = 0; i < 8; i++) pv[i] = sctr[half][oct * 8 + i];
      short8 hi, lo;
      #pragma unroll
      for (int i = 0; i < 8; i++) {
        short h = bf16_rne(pv[i]);
        hi[i] = h;
        lo[i] = bf16_rne(pv[i] - bf16_tof(h));
      }
      size_t fi = frag_idx(c, oct);
      Apk[fi] = hi;
      Apk[fi + 64] = lo;
    }
  }
}

// K2: MFMA dist (128x128 tile, 4 waves of 64x64 = 2x2 32x32x16), split-bf16.
// Epilogue: per-class max/min reduced across j-half waves in LDS, then ONE
// plain coalesced store per class per block. No atomics, no fences.
__global__ __launch_bounds__(256) void dist_kernel(
    const short8* __restrict__ Apk, const short8* __restrict__ Bpk,
    const float* __restrict__ x2, const float* __restrict__ c2,
    const int* __restrict__ targets,
    float* __restrict__ dp_part, float* __restrict__ dn_part) {
  __shared__ float sc2[128];
  __shared__ float sx2[128];
  __shared__ int stgt[128];
  __shared__ float redp[4][64];
  __shared__ float redn[4][64];

  int tid = threadIdx.x;
  int jbase = blockIdx.x * 128;
  int cbase = blockIdx.y * 128;
  int wave = tid >> 6, lane = tid & 63;
  int wm = wave >> 1, wn = wave & 1;

  if (tid < 128) {
    sc2[tid] = c2[cbase + tid];
    sx2[tid] = x2[jbase + tid];
    stgt[tid] = targets[jbase + tid];
  }

  f32x16 acc[2][2];
  #pragma unroll
  for (int i = 0; i < 2; i++)
    #pragma unroll
    for (int j = 0; j < 2; j++)
      acc[i][j] = (f32x16)(0.f);

  int mtg0 = (cbase >> 5) + wm * 2;
  int ntg0 = (jbase >> 5) + wn * 2;

  #pragma unroll 2
  for (int ks = 0; ks < 8; ks++) {
    bf16x8 a[2][2], b[2][2];  // [tile][plane]
    #pragma unroll
    for (int mt = 0; mt < 2; mt++) {
      size_t base = (size_t)(((mtg0 + mt) * 8 + ks) * 2) * 64 + lane;
      a[mt][0] = Apk[base];
      a[mt][1] = Apk[base + 64];
    }
    #pragma unroll
    for (int nt = 0; nt < 2; nt++) {
      size_t base = (size_t)(((ntg0 + nt) * 8 + ks) * 2) * 64 + lane;
      b[nt][0] = Bpk[base];
      b[nt][1] = Bpk[base + 64];
    }
    #pragma unroll
    for (int mt = 0; mt < 2; mt++)
      #pragma unroll
      for (int nt = 0; nt < 2; nt++) {
        acc[mt][nt] = __builtin_amdgcn_mfma_f32_32x32x16_bf16(a[mt][0], b[nt][0], acc[mt][nt], 0, 0, 0);
        acc[mt][nt] = __builtin_amdgcn_mfma_f32_32x32x16_bf16(a[mt][0], b[nt][1], acc[mt][nt], 0, 0, 0);
        acc[mt][nt] = __builtin_amdgcn_mfma_f32_32x32x16_bf16(a[mt][1], b[nt][0], acc[mt][nt], 0, 0, 0);
      }
  }

  __syncthreads();  // staging visible

  int hf = lane >> 5;
  int col = lane & 31;
  #pragma unroll
  for (int mt = 0; mt < 2; mt++) {
    #pragma unroll
    for (int r = 0; r < 16; r++) {
      int rowl = (r & 3) + 8 * (r >> 2) + 4 * hf;
      int c_loc = wm * 64 + mt * 32 + rowl;
      int cg = cbase + c_loc;
      float c2v = sc2[c_loc];
      float pmax = -INFINITY, nmin = INFINITY;
      #pragma unroll
      for (int nt = 0; nt < 2; nt++) {
        int j_loc = wn * 64 + nt * 32 + col;
        float d2 = c2v + sx2[j_loc] - 2.f * acc[mt][nt][r];
        if (stgt[j_loc] == cg) pmax = fmaxf(pmax, d2);
        else                   nmin = fminf(nmin, d2);
      }
      #pragma unroll
      for (int m = 1; m < 32; m <<= 1) {
        pmax = fmaxf(pmax, __shfl_xor(pmax, m));
        nmin = fminf(nmin, __shfl_xor(nmin, m));
      }
      if (col == 0) {
        redp[wave][mt * 32 + rowl] = pmax;
        redn[wave][mt * 32 + rowl] = nmin;
      }
    }
  }
  __syncthreads();
  if (tid < 128) {
    int wmx = tid >> 6, idx = tid & 63;
    float dp = fmaxf(redp[wmx * 2][idx], redp[wmx * 2 + 1][idx]);
    float dn = fminf(redn[wmx * 2][idx], redn[wmx * 2 + 1][idx]);
    size_t slot = (size_t)blockIdx.x * NCLS + cbase + tid;
    dp_part[slot] = dp;
    dn_part[slot] = dn;
  }
}

// K3: 8 blocks x 128 threads (thread = class). Reduce 64 partials/class
// (coalesced), weighted block reduction, atomicAdd into out (pre-zeroed).
__global__ __launch_bounds__(128) void finalize_kernel(
    const float* __restrict__ dp_part, const float* __restrict__ dn_part,
    const int* __restrict__ counts, float* __restrict__ out) {
  int c = blockIdx.x * 128 + threadIdx.x;
  float dp = -INFINITY, dn = INFINITY;
  #pragma unroll 8
  for (int p = 0; p < NPART; p++) {
    dp = fmaxf(dp, dp_part[(size_t)p * NCLS + c]);
    dn = fminf(dn, dn_part[(size_t)p * NCLS + c]);
  }
  int cnt = counts[c];
  float ls = 0.f, ps = 0.f;
  if (cnt > 0) {
    ls = (float)cnt * fmaxf(dp - dn + MARGIN_V, 0.f);
    ps = (float)cnt * ((dn > dp) ? 1.f : 0.f);
  }
  #pragma unroll
  for (int sh = 32; sh > 0; sh >>= 1) {
    ls += __shfl_down(ls, sh);
    ps += __shfl_down(ps, sh);
  }
  __shared__ float sl[2], sp[2];
  int wave = threadIdx.x >> 6, lane = threadIdx.x & 63;
  if (lane == 0) { sl[wave] = ls; sp[wave] = ps; }
  __syncthreads();
  if (threadIdx.x == 0) {
    atomicAdd(&out[0], (sl[0] + sl[1]) / (float)N_SAMPLES);
    atomicAdd(&out[1], (sp[0] + sp[1]) / (float)N_SAMPLES);
  }
}

extern "C" void kernel_launch(void* const* d_in, const int* in_sizes, int n_in,
                              void* d_out, int out_size, void* d_ws, size_t ws_size,
                              hipStream_t stream) {
  const float* inputs = (const float*)d_in[0];
  const int* targets = (const int*)d_in[1];
  float* out = (float*)d_out;

  char* w = (char*)d_ws;
  float* x2 = (float*)w;            w += (size_t)N_SAMPLES * 4;
  float* c2 = (float*)w;            w += (size_t)NCLS * 4;
  int* counts = (int*)w;            w += (size_t)NCLS * 4;
  float* dp_part = (float*)w;       w += (size_t)NPART * NCLS * 4;      // 256 KB
  float* dn_part = (float*)w;       w += (size_t)NPART * NCLS * 4;      // 256 KB
  short8* Apk = (short8*)w;         w += (size_t)NCLS * DIM * 2 * 2;    // 512 KB
  short8* Bpk = (short8*)w;         w += (size_t)N_SAMPLES * DIM * 2 * 2;  // 4 MB

  hipMemsetAsync(d_out, 0, 2 * sizeof(float), stream);  // atomicAdd targets
  pack_kernel<<<N_SAMPLES / 16 + NCLS / 2, 256, 0, stream>>>(
      inputs, targets, x2, c2, counts, Apk, Bpk);
  dist_kernel<<<dim3(DIST_GX, DIST_GY), 256, 0, stream>>>(
      Apk, Bpk, x2, c2, targets, dp_part, dn_part);
  finalize_kernel<<<8, 128, 0, stream>>>(dp_part, dn_part, counts, out);
}